// Round 1
// baseline (9514.296 us; speedup 1.0000x reference)
//
#include <hip/hip_runtime.h>
#include <math.h>

#define DIMX 768
#define FFX  3072
#define SX   6
#define VX   32000
#define BX   2
#define TX   1024
#define BT   (BX*TX)

__device__ __forceinline__ float gelu_f(float x){
    float x3 = x*x*x;
    return 0.5f*x*(1.0f + tanhf(0.7978845608028654f*(x + 0.044715f*x3)));
}
__device__ __forceinline__ float softplus_f(float x){
    return fmaxf(x,0.0f) + log1pf(expf(-fabsf(x)));
}

// block = 256 threads (4 waves) everywhere
__device__ __forceinline__ float block_reduce_sum(float v, volatile float* sbuf){
    #pragma unroll
    for(int off=32; off>0; off>>=1) v += __shfl_down(v, off, 64);
    int wid = threadIdx.x >> 6, lane = threadIdx.x & 63;
    __syncthreads();               // protect sbuf against previous use
    if(lane==0) sbuf[wid] = v;
    __syncthreads();
    return sbuf[0]+sbuf[1]+sbuf[2]+sbuf[3];
}

// ---------------- embed + pi init ----------------
__global__ void k_embed(const int* __restrict__ x, const float* __restrict__ emb,
                        const float* __restrict__ pos, float* __restrict__ h,
                        float* __restrict__ pi){
    int tok = blockIdx.x;
    int t = tok % TX;
    int id = x[tok];
    const float* er = emb + (long)id*DIMX;
    const float* pr = pos + (long)t*DIMX;
    float* hr = h + (long)tok*DIMX;
    for(int d=threadIdx.x; d<DIMX; d+=blockDim.x) hr[d] = er[d] + pr[d];
    if(threadIdx.x < SX) pi[tok*SX+threadIdx.x] = (threadIdx.x==2)?1.0f:0.0f;
}

// ---------------- generic fp32 GEMM (NN), C = act(A@B + bias) ----------------
// A: MxK row-major, B: KxN row-major. M%64==0, N%64==0, K%16==0.
// ACT: 0 none, 1 gelu, 2 softplus+0.1
template<int ACT>
__global__ void k_gemm_nn(const float* __restrict__ A, const float* __restrict__ B,
                          const float* __restrict__ bias, float* __restrict__ C,
                          int M, int N, int K){
    __shared__ float As[16][68];
    __shared__ float Bs[16][68];
    int tx = threadIdx.x & 15, ty = threadIdx.x >> 4;
    int bm = blockIdx.y * 64, bn = blockIdx.x * 64;
    float acc[4][4] = {};
    int la_c = threadIdx.x & 15;   // k within tile
    int la_r = threadIdx.x >> 4;   // row base
    int lb_r = threadIdx.x >> 6;   // k row base (0..3)
    int lb_c = threadIdx.x & 63;   // n col
    for(int k0=0; k0<K; k0+=16){
        #pragma unroll
        for(int i=0;i<4;i++)
            As[la_c][la_r + 16*i] = A[(long)(bm + la_r + 16*i)*K + k0 + la_c];
        #pragma unroll
        for(int i=0;i<4;i++)
            Bs[lb_r + 4*i][lb_c] = B[(long)(k0 + lb_r + 4*i)*N + bn + lb_c];
        __syncthreads();
        #pragma unroll
        for(int k=0;k<16;k++){
            float4 a4 = *(const float4*)&As[k][ty*4];
            float4 b4 = *(const float4*)&Bs[k][tx*4];
            float av[4]={a4.x,a4.y,a4.z,a4.w}, bv[4]={b4.x,b4.y,b4.z,b4.w};
            #pragma unroll
            for(int i=0;i<4;i++)
                #pragma unroll
                for(int j=0;j<4;j++)
                    acc[i][j] += av[i]*bv[j];
        }
        __syncthreads();
    }
    #pragma unroll
    for(int i=0;i<4;i++){
        int m = bm + ty*4 + i;
        #pragma unroll
        for(int j=0;j<4;j++){
            int n = bn + tx*4 + j;
            float v = acc[i][j] + (bias ? bias[n] : 0.0f);
            if(ACT==1) v = gelu_f(v);
            else if(ACT==2) v = softplus_f(v) + 0.1f;
            C[(long)m*N + n] = v;
        }
    }
}

// ---------------- bank second GEMM with pi-scaled accumulate epilogue ----------------
// C[m,n] (s==0 ? = : +=) pi[m*6+s] * (A@B + bias[n])
__global__ void k_gemm_bank2(const float* __restrict__ A, const float* __restrict__ B,
                             const float* __restrict__ bias, float* __restrict__ C,
                             const float* __restrict__ pi, int s,
                             int M, int N, int K){
    __shared__ float As[16][68];
    __shared__ float Bs[16][68];
    int tx = threadIdx.x & 15, ty = threadIdx.x >> 4;
    int bm = blockIdx.y * 64, bn = blockIdx.x * 64;
    float acc[4][4] = {};
    int la_c = threadIdx.x & 15;
    int la_r = threadIdx.x >> 4;
    int lb_r = threadIdx.x >> 6;
    int lb_c = threadIdx.x & 63;
    for(int k0=0; k0<K; k0+=16){
        #pragma unroll
        for(int i=0;i<4;i++)
            As[la_c][la_r + 16*i] = A[(long)(bm + la_r + 16*i)*K + k0 + la_c];
        #pragma unroll
        for(int i=0;i<4;i++)
            Bs[lb_r + 4*i][lb_c] = B[(long)(k0 + lb_r + 4*i)*N + bn + lb_c];
        __syncthreads();
        #pragma unroll
        for(int k=0;k<16;k++){
            float4 a4 = *(const float4*)&As[k][ty*4];
            float4 b4 = *(const float4*)&Bs[k][tx*4];
            float av[4]={a4.x,a4.y,a4.z,a4.w}, bv[4]={b4.x,b4.y,b4.z,b4.w};
            #pragma unroll
            for(int i=0;i<4;i++)
                #pragma unroll
                for(int j=0;j<4;j++)
                    acc[i][j] += av[i]*bv[j];
        }
        __syncthreads();
    }
    #pragma unroll
    for(int i=0;i<4;i++){
        int m = bm + ty*4 + i;
        float p = pi[m*SX + s];
        #pragma unroll
        for(int j=0;j<4;j++){
            int n = bn + tx*4 + j;
            float v = p * (acc[i][j] + bias[n]);
            long ci = (long)m*N + n;
            if(s==0) C[ci] = v; else C[ci] += v;
        }
    }
}

// ---------------- final logits GEMM (NT): C = alpha * A @ B^T ----------------
// A: MxK row, B: NxK row (emb_w). M%64==0, N%64==0, K%16==0.
__global__ void k_gemm_nt(const float* __restrict__ A, const float* __restrict__ B,
                          float* __restrict__ C, int M, int N, int K, float alpha){
    __shared__ float As[16][68];
    __shared__ float Bs[16][68];
    int tx = threadIdx.x & 15, ty = threadIdx.x >> 4;
    int bm = blockIdx.y * 64, bn = blockIdx.x * 64;
    float acc[4][4] = {};
    int la_c = threadIdx.x & 15;
    int la_r = threadIdx.x >> 4;
    int lb_k = threadIdx.x & 15;   // k
    int lb_n = threadIdx.x >> 4;   // n base
    for(int k0=0; k0<K; k0+=16){
        #pragma unroll
        for(int i=0;i<4;i++)
            As[la_c][la_r + 16*i] = A[(long)(bm + la_r + 16*i)*K + k0 + la_c];
        #pragma unroll
        for(int i=0;i<4;i++)
            Bs[lb_k][lb_n + 16*i] = B[(long)(bn + lb_n + 16*i)*K + k0 + lb_k];
        __syncthreads();
        #pragma unroll
        for(int k=0;k<16;k++){
            float4 a4 = *(const float4*)&As[k][ty*4];
            float4 b4 = *(const float4*)&Bs[k][tx*4];
            float av[4]={a4.x,a4.y,a4.z,a4.w}, bv[4]={b4.x,b4.y,b4.z,b4.w};
            #pragma unroll
            for(int i=0;i<4;i++)
                #pragma unroll
                for(int j=0;j<4;j++)
                    acc[i][j] += av[i]*bv[j];
        }
        __syncthreads();
    }
    #pragma unroll
    for(int i=0;i<4;i++){
        int m = bm + ty*4 + i;
        #pragma unroll
        for(int j=0;j<4;j++){
            int n = bn + tx*4 + j;
            C[(long)m*N + n] = alpha * acc[i][j];
        }
    }
}

// ---------------- layernorm (per token) out = (in-mean)*rstd*g + b ----------------
__global__ void k_ln(const float* __restrict__ in, float* __restrict__ out,
                     const float* __restrict__ g, const float* __restrict__ b){
    int tok = blockIdx.x;
    const float* r = in + (long)tok*DIMX;
    __shared__ float row[DIMX];
    __shared__ float sbuf[4];
    float lsum = 0;
    for(int d=threadIdx.x; d<DIMX; d+=blockDim.x){ float v=r[d]; row[d]=v; lsum+=v; }
    float mean = block_reduce_sum(lsum, sbuf) * (1.0f/DIMX);
    float lv = 0;
    for(int d=threadIdx.x; d<DIMX; d+=blockDim.x){ float dv=row[d]-mean; lv+=dv*dv; }
    float var = block_reduce_sum(lv, sbuf) * (1.0f/DIMX);
    float rstd = rsqrtf(var + 1e-5f);
    for(int d=threadIdx.x; d<DIMX; d+=blockDim.x)
        out[(long)tok*DIMX+d] = (row[d]-mean)*rstd*g[d] + b[d];
}

// ---------------- fused: kz = t1@tr_w2+b, K=softmax(6x6), pi_ev = pi@K ----------------
__global__ void k_trans(const float* __restrict__ t1, const float* __restrict__ w2,
                        const float* __restrict__ b2, const float* __restrict__ pi,
                        float* __restrict__ pi_ev){
    int tok = blockIdx.x;
    const float* a = t1 + (long)tok*(2*DIMX);
    float acc[36];
    #pragma unroll
    for(int j=0;j<36;j++) acc[j]=0.0f;
    for(int k=threadIdx.x; k<2*DIMX; k+=blockDim.x){
        float av = a[k];
        const float* wr = w2 + (long)k*36;
        #pragma unroll
        for(int j=0;j<36;j++) acc[j] += av*wr[j];
    }
    __shared__ float red[4*36];
    __shared__ float kz_s[36];
    __shared__ float K_s[36];
    int lane = threadIdx.x & 63, wid = threadIdx.x >> 6;
    #pragma unroll
    for(int j=0;j<36;j++){
        float v = acc[j];
        #pragma unroll
        for(int off=32;off>0;off>>=1) v += __shfl_down(v,off,64);
        if(lane==0) red[wid*36+j]=v;
    }
    __syncthreads();
    if(threadIdx.x<36)
        kz_s[threadIdx.x] = red[threadIdx.x]+red[36+threadIdx.x]+red[72+threadIdx.x]
                           +red[108+threadIdx.x] + b2[threadIdx.x];
    __syncthreads();
    if(threadIdx.x<SX){
        int s = threadIdx.x;
        float mx=-1e30f;
        for(int u=0;u<SX;u++) mx=fmaxf(mx,kz_s[s*SX+u]);
        float e[SX]; float sum=0;
        for(int u=0;u<SX;u++){ e[u]=expf(kz_s[s*SX+u]-mx); sum+=e[u]; }
        for(int u=0;u<SX;u++) K_s[s*SX+u]=e[u]/sum;
    }
    __syncthreads();
    if(threadIdx.x<SX){
        int u = threadIdx.x;
        float v=0;
        for(int s=0;s<SX;s++) v += pi[tok*SX+s]*K_s[s*SX+u];
        pi_ev[tok*SX+u]=v;
    }
}

// ---------------- fused: ev = mun@ev_w+b, pi update (softmax, top-2, renorm) ----------------
__global__ void k_pi_update(const float* __restrict__ mun, const float* __restrict__ ev_w,
                            const float* __restrict__ ev_b, const float* __restrict__ pi_ev,
                            float* __restrict__ pi){
    int tok = blockIdx.x;
    const float* r = mun + (long)tok*DIMX;
    float acc[SX] = {};
    for(int d=threadIdx.x; d<DIMX; d+=blockDim.x){
        float v = r[d];
        const float* w = ev_w + (long)d*SX;
        #pragma unroll
        for(int s=0;s<SX;s++) acc[s] += v*w[s];
    }
    __shared__ float red[4*SX];
    int lane = threadIdx.x & 63, wid = threadIdx.x >> 6;
    #pragma unroll
    for(int s=0;s<SX;s++){
        float v = acc[s];
        #pragma unroll
        for(int off=32;off>0;off>>=1) v += __shfl_down(v,off,64);
        if(lane==0) red[wid*SX+s]=v;
    }
    __syncthreads();
    if(threadIdx.x==0){
        float ev[SX], pn[SX];
        float mx=-1e30f;
        for(int s=0;s<SX;s++){
            ev[s] = (red[s]+red[SX+s]+red[2*SX+s]+red[3*SX+s] + ev_b[s]) * 2.0f; // /0.5
            mx = fmaxf(mx, ev[s]);
        }
        float sum=0;
        for(int s=0;s<SX;s++){ ev[s]=expf(ev[s]-mx); sum+=ev[s]; }
        float psum=0;
        for(int s=0;s<SX;s++){ pn[s]=pi_ev[tok*SX+s]*(ev[s]/sum); psum+=pn[s]; }
        float inv = 1.0f/fmaxf(psum,1e-8f);
        for(int s=0;s<SX;s++) pn[s]*=inv;
        // top-2, ties -> lower index first (strict >)
        int i1=0; for(int s=1;s<SX;s++) if(pn[s]>pn[i1]) i1=s;
        int i2=-1;
        for(int s=0;s<SX;s++){ if(s==i1) continue; if(i2<0 || pn[s]>pn[i2]) i2=s; }
        float out[SX]; float s2=0;
        for(int s=0;s<SX;s++){ out[s]=(s==i1||s==i2)?pn[s]:0.0f; s2+=out[s]; }
        float inv2 = 1.0f/fmaxf(s2,1e-8f);
        for(int s=0;s<SX;s++) pi[tok*SX+s]=out[s]*inv2;
    }
}

// ---------------- fused attention: sc, softmax over 4 offsets, messages, *pi3, ln(3) ----------------
__global__ void k_attn(const float* __restrict__ q, const float* __restrict__ kk,
                       const float* __restrict__ vv, const float* __restrict__ pi,
                       const float* __restrict__ g3, const float* __restrict__ b3,
                       float* __restrict__ msg){
    const int offs[4] = {-2,-1,1,2};
    const float RSQ = 0.03608439182435161f; // 1/sqrt(768)
    int tok = blockIdx.x;
    int b = tok / TX, t = tok % TX;
    const float* qr = q + (long)tok*DIMX;
    float sc[4] = {0,0,0,0};
    for(int d=threadIdx.x; d<DIMX; d+=blockDim.x){
        float qv = qr[d];
        #pragma unroll
        for(int o=0;o<4;o++){
            int tt = t + offs[o];
            if(tt>=0 && tt<TX) sc[o] += qv * kk[((long)(b*TX+tt))*DIMX + d];
        }
    }
    __shared__ float red[4*4];
    __shared__ float wts[4];
    int lane = threadIdx.x & 63, wid = threadIdx.x >> 6;
    #pragma unroll
    for(int o=0;o<4;o++){
        float v = sc[o];
        #pragma unroll
        for(int off=32;off>0;off>>=1) v += __shfl_down(v,off,64);
        if(lane==0) red[wid*4+o]=v;
    }
    __syncthreads();
    if(threadIdx.x==0){
        float s[4], mx=-1e30f;
        for(int o=0;o<4;o++){
            int tt = t + offs[o];
            s[o] = (tt>=0 && tt<TX) ? (red[o]+red[4+o]+red[8+o]+red[12+o])*RSQ : -1e9f;
            mx = fmaxf(mx, s[o]);
        }
        float sum=0;
        for(int o=0;o<4;o++){ s[o]=expf(s[o]-mx); sum+=s[o]; }
        for(int o=0;o<4;o++) wts[o]=s[o]/sum;
    }
    __syncthreads();
    float p3 = pi[tok*SX+3];
    __shared__ float row[DIMX];
    __shared__ float sbuf[4];
    float lsum = 0;
    for(int d=threadIdx.x; d<DIMX; d+=blockDim.x){
        float m = 0;
        #pragma unroll
        for(int o=0;o<4;o++){
            int tt = t + offs[o];
            if(tt>=0 && tt<TX) m += wts[o]*vv[((long)(b*TX+tt))*DIMX + d];
        }
        m *= p3;
        row[d] = m; lsum += m;
    }
    float mean = block_reduce_sum(lsum, sbuf) * (1.0f/DIMX);
    float lv = 0;
    for(int d=threadIdx.x; d<DIMX; d+=blockDim.x){ float dv=row[d]-mean; lv+=dv*dv; }
    float var = block_reduce_sum(lv, sbuf) * (1.0f/DIMX);
    float rstd = rsqrtf(var + 1e-5f);
    for(int d=threadIdx.x; d<DIMX; d+=blockDim.x)
        msg[(long)tok*DIMX+d] = (row[d]-mean)*rstd*g3[d] + b3[d];
}

// ---------------- fused write-update + ln(5) + add 0.1*so ----------------
__global__ void k_update(const float* __restrict__ dlamz, const float* __restrict__ mhat,
                         const float* __restrict__ muwn, const float* __restrict__ so,
                         const float* __restrict__ pi, float* __restrict__ mu,
                         float* __restrict__ lam,
                         const float* __restrict__ g5, const float* __restrict__ b5){
    int tok = blockIdx.x;
    float g = pi[tok*SX+4];
    __shared__ float row[DIMX];
    __shared__ float sbuf[4];
    float lsum = 0;
    for(int d=threadIdx.x; d<DIMX; d+=blockDim.x){
        long i = (long)tok*DIMX + d;
        float dl = g * softplus_f(dlamz[i]);
        float l  = lam[i];
        float ln_ = l + dl;
        float v = (l*muwn[i] + dl*mhat[i]) / ln_;
        lam[i] = ln_;
        row[d] = v; lsum += v;
    }
    float mean = block_reduce_sum(lsum, sbuf) * (1.0f/DIMX);
    float lv = 0;
    for(int d=threadIdx.x; d<DIMX; d+=blockDim.x){ float dv=row[d]-mean; lv+=dv*dv; }
    float var = block_reduce_sum(lv, sbuf) * (1.0f/DIMX);
    float rstd = rsqrtf(var + 1e-5f);
    for(int d=threadIdx.x; d<DIMX; d+=blockDim.x){
        long i = (long)tok*DIMX + d;
        mu[i] = (row[d]-mean)*rstd*g5[d] + b5[d] + 0.1f*so[i];
    }
}

extern "C" void kernel_launch(void* const* d_in, const int* in_sizes, int n_in,
                              void* d_out, int out_size, void* d_ws, size_t ws_size,
                              hipStream_t stream){
    const int*   x       = (const int*)  d_in[0];
    const float* emb_w   = (const float*)d_in[1];
    const float* pos_w   = (const float*)d_in[2];
    const float* mu_w    = (const float*)d_in[3];
    const float* mu_b    = (const float*)d_in[4];
    const float* lam_w   = (const float*)d_in[5];
    const float* lam_b   = (const float*)d_in[6];
    const float* tr_w1   = (const float*)d_in[7];
    const float* tr_b1   = (const float*)d_in[8];
    const float* tr_w2   = (const float*)d_in[9];
    const float* tr_b2   = (const float*)d_in[10];
    const float* bank_w1 = (const float*)d_in[11];
    const float* bank_b1 = (const float*)d_in[12];
    const float* bank_w2 = (const float*)d_in[13];
    const float* bank_b2 = (const float*)d_in[14];
    const float* ev_w    = (const float*)d_in[15];
    const float* ev_b    = (const float*)d_in[16];
    const float* rt_q    = (const float*)d_in[17];
    const float* rt_k    = (const float*)d_in[18];
    const float* rt_v    = (const float*)d_in[19];
    const float* wr_lam_w= (const float*)d_in[20];
    const float* wr_lam_b= (const float*)d_in[21];
    const float* wr_mu_w = (const float*)d_in[22];
    const float* wr_mu_b = (const float*)d_in[23];
    const float* ln_g    = (const float*)d_in[24];
    const float* ln_b    = (const float*)d_in[25];

    float* ws  = (float*)d_ws;
    float* h   = ws;                       // BT*DIMX
    float* mu  = h   + (long)BT*DIMX;      // BT*DIMX
    float* lam = mu  + (long)BT*DIMX;      // BT*DIMX
    float* mun = lam + (long)BT*DIMX;      // BT*DIMX (reused for ln0/ln2/ln4/ln6)
    float* so  = mun + (long)BT*DIMX;      // BT*DIMX
    float* t1  = so  + (long)BT*DIMX;      // BT*2*DIMX
    float* hb  = t1  + (long)BT*2*DIMX;    // BT*FFX
    float* pi  = hb  + (long)BT*FFX;       // BT*SX
    float* piv = pi  + (long)BT*SX;        // BT*SX
    // aliases (lifetimes verified disjoint)
    float* q     = t1;                     // t1 dead after k_trans
    float* kk    = t1 + (long)BT*DIMX;
    float* vv    = h;                      // h dead after mu/lam GEMMs
    float* msg   = hb;                     // hb dead after bank GEMMs of the step
    float* dlamz = hb + (long)BT*DIMX;
    float* mhat  = hb + 2L*BT*DIMX;

    dim3 blk(256);
    dim3 g768(DIMX/64, BT/64);

    k_embed<<<BT, blk, 0, stream>>>(x, emb_w, pos_w, h, pi);
    k_gemm_nn<0><<<g768, blk, 0, stream>>>(h, mu_w,  mu_b,  mu,  BT, DIMX, DIMX);
    k_gemm_nn<2><<<g768, blk, 0, stream>>>(h, lam_w, lam_b, lam, BT, DIMX, DIMX);

    for(int step=0; step<3; step++){
        // transition MLP -> pi_ev
        k_gemm_nn<1><<<dim3(2*DIMX/64, BT/64), blk, 0, stream>>>(mu, tr_w1, tr_b1, t1, BT, 2*DIMX, DIMX);
        k_trans<<<BT, blk, 0, stream>>>(t1, tr_w2, tr_b2, pi, piv);
        // bank MoE
        k_ln<<<BT, blk, 0, stream>>>(mu, mun, ln_g+0*DIMX, ln_b+0*DIMX);
        for(int s=0; s<SX; s++){
            k_gemm_nn<1><<<dim3(FFX/64, BT/64), blk, 0, stream>>>(
                mun, bank_w1+(long)s*DIMX*FFX, bank_b1+(long)s*FFX, hb, BT, FFX, DIMX);
            k_gemm_bank2<<<dim3(DIMX/64, BT/64), blk, 0, stream>>>(
                hb, bank_w2+(long)s*FFX*DIMX, bank_b2+(long)s*DIMX, so, pi, s, BT, DIMX, FFX);
        }
        k_ln<<<BT, blk, 0, stream>>>(so, so, ln_g+1*DIMX, ln_b+1*DIMX);  // in-place safe (row cached in LDS)
        // pi update (uses mun = ln0, piv)
        k_pi_update<<<BT, blk, 0, stream>>>(mun, ev_w, ev_b, piv, pi);
        // routed attention
        k_ln<<<BT, blk, 0, stream>>>(mu, mun, ln_g+2*DIMX, ln_b+2*DIMX);
        k_gemm_nn<0><<<g768, blk, 0, stream>>>(mun, rt_q, nullptr, q,  BT, DIMX, DIMX);
        k_gemm_nn<0><<<g768, blk, 0, stream>>>(mun, rt_k, nullptr, kk, BT, DIMX, DIMX);
        k_gemm_nn<0><<<g768, blk, 0, stream>>>(mun, rt_v, nullptr, vv, BT, DIMX, DIMX);
        k_attn<<<BT, blk, 0, stream>>>(q, kk, vv, pi, ln_g+3*DIMX, ln_b+3*DIMX, msg);
        // write update
        k_ln<<<BT, blk, 0, stream>>>(mu, mun, ln_g+4*DIMX, ln_b+4*DIMX);
        k_gemm_nn<0><<<g768, blk, 0, stream>>>(msg, wr_lam_w, wr_lam_b, dlamz, BT, DIMX, DIMX);
        k_gemm_nn<0><<<g768, blk, 0, stream>>>(msg, wr_mu_w,  wr_mu_b,  mhat,  BT, DIMX, DIMX);
        k_update<<<BT, blk, 0, stream>>>(dlamz, mhat, mun, so, pi, mu, lam, ln_g+5*DIMX, ln_b+5*DIMX);
    }
    // final LN + logits
    k_ln<<<BT, blk, 0, stream>>>(mu, mun, ln_g+6*DIMX, ln_b+6*DIMX);
    k_gemm_nt<<<dim3(VX/64, BT/64), blk, 0, stream>>>(mun, emb_w, (float*)d_out,
                                                      BT, VX, DIMX, 0.03608439182435161f);
}

// Round 2
// 5734.921 us; speedup vs baseline: 1.6590x; 1.6590x over previous
//
#include <hip/hip_runtime.h>
#include <math.h>

#define DIMX 768
#define FFX  3072
#define SX   6
#define VX   32000
#define BX   2
#define TX   1024
#define BT   (BX*TX)
#define LDK  40   // LDS row stride (bf16 elems) for 32-wide K tiles, padded

typedef __bf16 bf16x8 __attribute__((ext_vector_type(8)));
typedef __bf16 bf16x4 __attribute__((ext_vector_type(4)));
typedef float  f32x4  __attribute__((ext_vector_type(4)));

__device__ __forceinline__ float gelu_f(float x){
    float x3 = x*x*x;
    return 0.5f*x*(1.0f + tanhf(0.7978845608028654f*(x + 0.044715f*x3)));
}
__device__ __forceinline__ float softplus_f(float x){
    return fmaxf(x,0.0f) + log1pf(expf(-fabsf(x)));
}

__device__ __forceinline__ float block_reduce_sum(float v, volatile float* sbuf){
    #pragma unroll
    for(int off=32; off>0; off>>=1) v += __shfl_down(v, off, 64);
    int wid = threadIdx.x >> 6, lane = threadIdx.x & 63;
    __syncthreads();
    if(lane==0) sbuf[wid] = v;
    __syncthreads();
    return sbuf[0]+sbuf[1]+sbuf[2]+sbuf[3];
}

// ---------------- embed + pi init ----------------
__global__ void k_embed(const int* __restrict__ x, const float* __restrict__ emb,
                        const float* __restrict__ pos, float* __restrict__ h,
                        float* __restrict__ pi){
    int tok = blockIdx.x;
    int t = tok % TX;
    int id = x[tok];
    const float* er = emb + (long)id*DIMX;
    const float* pr = pos + (long)t*DIMX;
    float* hr = h + (long)tok*DIMX;
    for(int d=threadIdx.x; d<DIMX; d+=blockDim.x) hr[d] = er[d] + pr[d];
    if(threadIdx.x < SX) pi[tok*SX+threadIdx.x] = (threadIdx.x==2)?1.0f:0.0f;
}

// ---------------- expert list init (step 0: all tokens -> expert 2) ----------------
__global__ void k_init_lists(int* __restrict__ gidx, int* __restrict__ cnt){
    int tid = blockIdx.x*blockDim.x + threadIdx.x;
    if(tid < SX*BT) gidx[tid] = (tid/BT == 2) ? (tid % BT) : BT;
    if(tid < SX) cnt[tid] = (tid==2) ? BT : 0;
}
__global__ void k_fill_lists(int* __restrict__ gidx, int* __restrict__ cnt){
    int tid = blockIdx.x*blockDim.x + threadIdx.x;
    if(tid < SX*BT) gidx[tid] = BT;
    if(tid < SX) cnt[tid] = 0;
}

// ---------------- fp32 -> bf16 elementwise (emb_w for logits) ----------------
__global__ void k_cvt_bf16(const float* __restrict__ in, __bf16* __restrict__ out, long n){
    long i = ((long)blockIdx.x*blockDim.x + threadIdx.x)*4;
    if(i+3 < n){
        float4 v = *(const float4*)&in[i];
        bf16x4 o;
        o[0]=(__bf16)v.x; o[1]=(__bf16)v.y; o[2]=(__bf16)v.z; o[3]=(__bf16)v.w;
        *(bf16x4*)&out[i] = o;
    }
}

// ---------------- generic fp32 GEMM (NN), C = act(A@B + bias) ----------------
template<int ACT>
__global__ void k_gemm_nn(const float* __restrict__ A, const float* __restrict__ B,
                          const float* __restrict__ bias, float* __restrict__ C,
                          int M, int N, int K){
    __shared__ float As[16][68];
    __shared__ float Bs[16][68];
    int tx = threadIdx.x & 15, ty = threadIdx.x >> 4;
    int bm = blockIdx.y * 64, bn = blockIdx.x * 64;
    float acc[4][4] = {};
    int la_c = threadIdx.x & 15;
    int la_r = threadIdx.x >> 4;
    int lb_r = threadIdx.x >> 6;
    int lb_c = threadIdx.x & 63;
    for(int k0=0; k0<K; k0+=16){
        #pragma unroll
        for(int i=0;i<4;i++)
            As[la_c][la_r + 16*i] = A[(long)(bm + la_r + 16*i)*K + k0 + la_c];
        #pragma unroll
        for(int i=0;i<4;i++)
            Bs[lb_r + 4*i][lb_c] = B[(long)(k0 + lb_r + 4*i)*N + bn + lb_c];
        __syncthreads();
        #pragma unroll
        for(int k=0;k<16;k++){
            float4 a4 = *(const float4*)&As[k][ty*4];
            float4 b4 = *(const float4*)&Bs[k][tx*4];
            float av[4]={a4.x,a4.y,a4.z,a4.w}, bv[4]={b4.x,b4.y,b4.z,b4.w};
            #pragma unroll
            for(int i=0;i<4;i++)
                #pragma unroll
                for(int j=0;j<4;j++)
                    acc[i][j] += av[i]*bv[j];
        }
        __syncthreads();
    }
    #pragma unroll
    for(int i=0;i<4;i++){
        int m = bm + ty*4 + i;
        #pragma unroll
        for(int j=0;j<4;j++){
            int n = bn + tx*4 + j;
            float v = acc[i][j] + (bias ? bias[n] : 0.0f);
            if(ACT==1) v = gelu_f(v);
            else if(ACT==2) v = softplus_f(v) + 0.1f;
            C[(long)m*N + n] = v;
        }
    }
}

// ---------------- gathered bank GEMM 1: hb[r] = gelu(mun[gidx[r]] @ w1 + b1) ----------------
__global__ void k_gemm_g1(const float* __restrict__ A, const float* __restrict__ B,
                          const float* __restrict__ bias, float* __restrict__ C,
                          const int* __restrict__ gidx, const int* __restrict__ cnt,
                          int s, int N, int K){
    int c = cnt[s];
    int bm = blockIdx.y * 64;
    if(bm >= c) return;
    const int* gid = gidx + s*BT;
    __shared__ float As[16][68];
    __shared__ float Bs[16][68];
    int tx = threadIdx.x & 15, ty = threadIdx.x >> 4;
    int bn = blockIdx.x * 64;
    float acc[4][4] = {};
    int la_c = threadIdx.x & 15;
    int la_r = threadIdx.x >> 4;
    int lb_r = threadIdx.x >> 6;
    int lb_c = threadIdx.x & 63;
    int rowA[4];
    #pragma unroll
    for(int i=0;i<4;i++){
        int tok = gid[bm + la_r + 16*i];
        rowA[i] = (tok < BT) ? tok : 0;
    }
    for(int k0=0; k0<K; k0+=16){
        #pragma unroll
        for(int i=0;i<4;i++)
            As[la_c][la_r + 16*i] = A[(long)rowA[i]*K + k0 + la_c];
        #pragma unroll
        for(int i=0;i<4;i++)
            Bs[lb_r + 4*i][lb_c] = B[(long)(k0 + lb_r + 4*i)*N + bn + lb_c];
        __syncthreads();
        #pragma unroll
        for(int k=0;k<16;k++){
            float4 a4 = *(const float4*)&As[k][ty*4];
            float4 b4 = *(const float4*)&Bs[k][tx*4];
            float av[4]={a4.x,a4.y,a4.z,a4.w}, bv[4]={b4.x,b4.y,b4.z,b4.w};
            #pragma unroll
            for(int i=0;i<4;i++)
                #pragma unroll
                for(int j=0;j<4;j++)
                    acc[i][j] += av[i]*bv[j];
        }
        __syncthreads();
    }
    #pragma unroll
    for(int i=0;i<4;i++){
        int m = bm + ty*4 + i;
        #pragma unroll
        for(int j=0;j<4;j++){
            int n = bn + tx*4 + j;
            C[(long)m*N + n] = gelu_f(acc[i][j] + bias[n]);
        }
    }
}

// ---------------- gathered bank GEMM 2: so[tok] += pi[tok,s] * (hb[r] @ w2 + b2) ----------------
__global__ void k_gemm_g2(const float* __restrict__ A, const float* __restrict__ B,
                          const float* __restrict__ bias, float* __restrict__ C,
                          const float* __restrict__ pi, const int* __restrict__ gidx,
                          const int* __restrict__ cnt, int s, int N, int K){
    int c = cnt[s];
    int bm = blockIdx.y * 64;
    if(bm >= c) return;
    const int* gid = gidx + s*BT;
    __shared__ float As[16][68];
    __shared__ float Bs[16][68];
    int tx = threadIdx.x & 15, ty = threadIdx.x >> 4;
    int bn = blockIdx.x * 64;
    float acc[4][4] = {};
    int la_c = threadIdx.x & 15;
    int la_r = threadIdx.x >> 4;
    int lb_r = threadIdx.x >> 6;
    int lb_c = threadIdx.x & 63;
    for(int k0=0; k0<K; k0+=16){
        #pragma unroll
        for(int i=0;i<4;i++)
            As[la_c][la_r + 16*i] = A[(long)(bm + la_r + 16*i)*K + k0 + la_c];
        #pragma unroll
        for(int i=0;i<4;i++)
            Bs[lb_r + 4*i][lb_c] = B[(long)(k0 + lb_r + 4*i)*N + bn + lb_c];
        __syncthreads();
        #pragma unroll
        for(int k=0;k<16;k++){
            float4 a4 = *(const float4*)&As[k][ty*4];
            float4 b4 = *(const float4*)&Bs[k][tx*4];
            float av[4]={a4.x,a4.y,a4.z,a4.w}, bv[4]={b4.x,b4.y,b4.z,b4.w};
            #pragma unroll
            for(int i=0;i<4;i++)
                #pragma unroll
                for(int j=0;j<4;j++)
                    acc[i][j] += av[i]*bv[j];
        }
        __syncthreads();
    }
    #pragma unroll
    for(int i=0;i<4;i++){
        int m = bm + ty*4 + i;
        int tok = gid[m];                     // == BT sentinel for padded rows
        float p = (m < c) ? pi[tok*SX + s] : 0.0f;
        #pragma unroll
        for(int j=0;j<4;j++){
            int n = bn + tx*4 + j;
            long ci = (long)tok*N + n;
            C[ci] += p * (acc[i][j] + bias[n]);
        }
    }
}

// ---------------- logits: bf16 MFMA NT GEMM, C = alpha * A @ B^T ----------------
// A: M x K fp32 (converted to bf16 in-kernel), B: N x K bf16 (pre-converted emb_w)
__global__ void k_logits_mfma(const float* __restrict__ A, const __bf16* __restrict__ Bw,
                              float* __restrict__ C, float alpha){
    __shared__ __bf16 Ah[128*LDK];
    __shared__ __bf16 Bh[128*LDK];
    int tid = threadIdx.x;
    int wave = tid>>6, lane = tid&63, ln = lane&15, quad = lane>>4;
    int bm = blockIdx.y*128, bn = blockIdx.x*128;
    int wm = (wave>>1)*64, wn = (wave&1)*64;
    f32x4 zero = {0.0f,0.0f,0.0f,0.0f};
    f32x4 acc[4][4];
    #pragma unroll
    for(int i=0;i<4;i++)
        #pragma unroll
        for(int j=0;j<4;j++) acc[i][j] = zero;
    for(int k0=0; k0<DIMX; k0+=32){
        // stage A tile (128x32 fp32 -> bf16), [m][k] padded LDK
        #pragma unroll
        for(int i=0;i<4;i++){
            int idx = tid + 256*i;
            int row = idx>>3, c4 = idx&7;
            float4 v = *(const float4*)&A[(long)(bm+row)*DIMX + k0 + c4*4];
            bf16x4 o;
            o[0]=(__bf16)v.x; o[1]=(__bf16)v.y; o[2]=(__bf16)v.z; o[3]=(__bf16)v.w;
            *(bf16x4*)&Ah[row*LDK + c4*4] = o;
        }
        // stage B tile (128x32 bf16 copy), [n][k] padded LDK
        #pragma unroll
        for(int i=0;i<2;i++){
            int idx = tid + 256*i;
            int row = idx>>2, c8 = idx&3;
            bf16x8 v = *(const bf16x8*)&Bw[(long)(bn+row)*DIMX + k0 + c8*8];
            *(bf16x8*)&Bh[row*LDK + c8*8] = v;
        }
        __syncthreads();
        bf16x8 af[4], bfr[4];
        #pragma unroll
        for(int i=0;i<4;i++) af[i]  = *(const bf16x8*)&Ah[(wm+i*16+ln)*LDK + quad*8];
        #pragma unroll
        for(int j=0;j<4;j++) bfr[j] = *(const bf16x8*)&Bh[(wn+j*16+ln)*LDK + quad*8];
        #pragma unroll
        for(int i=0;i<4;i++)
            #pragma unroll
            for(int j=0;j<4;j++)
                acc[i][j] = __builtin_amdgcn_mfma_f32_16x16x32_bf16(af[i], bfr[j], acc[i][j], 0,0,0);
        __syncthreads();
    }
    #pragma unroll
    for(int i=0;i<4;i++){
        #pragma unroll
        for(int j=0;j<4;j++){
            #pragma unroll
            for(int r=0;r<4;r++){
                int m = bm + wm + i*16 + quad*4 + r;
                int n = bn + wn + j*16 + ln;
                C[(long)m*VX + n] = alpha * acc[i][j][r];
            }
        }
    }
}

// ---------------- layernorm ----------------
__global__ void k_ln(const float* __restrict__ in, float* __restrict__ out,
                     const float* __restrict__ g, const float* __restrict__ b){
    int tok = blockIdx.x;
    const float* r = in + (long)tok*DIMX;
    __shared__ float row[DIMX];
    __shared__ float sbuf[4];
    float lsum = 0;
    for(int d=threadIdx.x; d<DIMX; d+=blockDim.x){ float v=r[d]; row[d]=v; lsum+=v; }
    float mean = block_reduce_sum(lsum, sbuf) * (1.0f/DIMX);
    float lv = 0;
    for(int d=threadIdx.x; d<DIMX; d+=blockDim.x){ float dv=row[d]-mean; lv+=dv*dv; }
    float var = block_reduce_sum(lv, sbuf) * (1.0f/DIMX);
    float rstd = rsqrtf(var + 1e-5f);
    for(int d=threadIdx.x; d<DIMX; d+=blockDim.x)
        out[(long)tok*DIMX+d] = (row[d]-mean)*rstd*g[d] + b[d];
}

// ---------------- fused: kz = t1@tr_w2+b, K=softmax(6x6), pi_ev = pi@K ----------------
__global__ void k_trans(const float* __restrict__ t1, const float* __restrict__ w2,
                        const float* __restrict__ b2, const float* __restrict__ pi,
                        float* __restrict__ pi_ev){
    int tok = blockIdx.x;
    const float* a = t1 + (long)tok*(2*DIMX);
    float acc[36];
    #pragma unroll
    for(int j=0;j<36;j++) acc[j]=0.0f;
    for(int k=threadIdx.x; k<2*DIMX; k+=blockDim.x){
        float av = a[k];
        const float* wr = w2 + (long)k*36;
        #pragma unroll
        for(int j=0;j<36;j++) acc[j] += av*wr[j];
    }
    __shared__ float red[4*36];
    __shared__ float kz_s[36];
    __shared__ float K_s[36];
    int lane = threadIdx.x & 63, wid = threadIdx.x >> 6;
    #pragma unroll
    for(int j=0;j<36;j++){
        float v = acc[j];
        #pragma unroll
        for(int off=32;off>0;off>>=1) v += __shfl_down(v,off,64);
        if(lane==0) red[wid*36+j]=v;
    }
    __syncthreads();
    if(threadIdx.x<36)
        kz_s[threadIdx.x] = red[threadIdx.x]+red[36+threadIdx.x]+red[72+threadIdx.x]
                           +red[108+threadIdx.x] + b2[threadIdx.x];
    __syncthreads();
    if(threadIdx.x<SX){
        int s = threadIdx.x;
        float mx=-1e30f;
        for(int u=0;u<SX;u++) mx=fmaxf(mx,kz_s[s*SX+u]);
        float e[SX]; float sum=0;
        for(int u=0;u<SX;u++){ e[u]=expf(kz_s[s*SX+u]-mx); sum+=e[u]; }
        for(int u=0;u<SX;u++) K_s[s*SX+u]=e[u]/sum;
    }
    __syncthreads();
    if(threadIdx.x<SX){
        int u = threadIdx.x;
        float v=0;
        for(int s=0;s<SX;s++) v += pi[tok*SX+s]*K_s[s*SX+u];
        pi_ev[tok*SX+u]=v;
    }
}

// ---------------- fused: ev, pi update (softmax, top-2, renorm) + expert-list append ----------------
__global__ void k_pi_update(const float* __restrict__ mun, const float* __restrict__ ev_w,
                            const float* __restrict__ ev_b, const float* __restrict__ pi_ev,
                            float* __restrict__ pi, int* __restrict__ gidx, int* __restrict__ cnt){
    int tok = blockIdx.x;
    const float* r = mun + (long)tok*DIMX;
    float acc[SX] = {};
    for(int d=threadIdx.x; d<DIMX; d+=blockDim.x){
        float v = r[d];
        const float* w = ev_w + (long)d*SX;
        #pragma unroll
        for(int s=0;s<SX;s++) acc[s] += v*w[s];
    }
    __shared__ float red[4*SX];
    int lane = threadIdx.x & 63, wid = threadIdx.x >> 6;
    #pragma unroll
    for(int s=0;s<SX;s++){
        float v = acc[s];
        #pragma unroll
        for(int off=32;off>0;off>>=1) v += __shfl_down(v,off,64);
        if(lane==0) red[wid*SX+s]=v;
    }
    __syncthreads();
    if(threadIdx.x==0){
        float ev[SX], pn[SX];
        float mx=-1e30f;
        for(int s=0;s<SX;s++){
            ev[s] = (red[s]+red[SX+s]+red[2*SX+s]+red[3*SX+s] + ev_b[s]) * 2.0f;
            mx = fmaxf(mx, ev[s]);
        }
        float sum=0;
        for(int s=0;s<SX;s++){ ev[s]=expf(ev[s]-mx); sum+=ev[s]; }
        float psum=0;
        for(int s=0;s<SX;s++){ pn[s]=pi_ev[tok*SX+s]*(ev[s]/sum); psum+=pn[s]; }
        float inv = 1.0f/fmaxf(psum,1e-8f);
        for(int s=0;s<SX;s++) pn[s]*=inv;
        int i1=0; for(int s=1;s<SX;s++) if(pn[s]>pn[i1]) i1=s;
        int i2=-1;
        for(int s=0;s<SX;s++){ if(s==i1) continue; if(i2<0 || pn[s]>pn[i2]) i2=s; }
        float out[SX]; float s2=0;
        for(int s=0;s<SX;s++){ out[s]=(s==i1||s==i2)?pn[s]:0.0f; s2+=out[s]; }
        float inv2 = 1.0f/fmaxf(s2,1e-8f);
        for(int s=0;s<SX;s++) pi[tok*SX+s]=out[s]*inv2;
        // append token to its live experts' lists
        #pragma unroll
        for(int k=0;k<2;k++){
            int si = (k==0)? i1 : i2;
            if(out[si]*inv2 > 0.0f){
                int pos = atomicAdd(&cnt[si], 1);
                gidx[si*BT + pos] = tok;
            }
        }
    }
}

// ---------------- fused attention ----------------
__global__ void k_attn(const float* __restrict__ q, const float* __restrict__ kk,
                       const float* __restrict__ vv, const float* __restrict__ pi,
                       const float* __restrict__ g3, const float* __restrict__ b3,
                       float* __restrict__ msg){
    const int offs[4] = {-2,-1,1,2};
    const float RSQ = 0.03608439182435161f;
    int tok = blockIdx.x;
    int b = tok / TX, t = tok % TX;
    const float* qr = q + (long)tok*DIMX;
    float sc[4] = {0,0,0,0};
    for(int d=threadIdx.x; d<DIMX; d+=blockDim.x){
        float qv = qr[d];
        #pragma unroll
        for(int o=0;o<4;o++){
            int tt = t + offs[o];
            if(tt>=0 && tt<TX) sc[o] += qv * kk[((long)(b*TX+tt))*DIMX + d];
        }
    }
    __shared__ float red[4*4];
    __shared__ float wts[4];
    int lane = threadIdx.x & 63, wid = threadIdx.x >> 6;
    #pragma unroll
    for(int o=0;o<4;o++){
        float v = sc[o];
        #pragma unroll
        for(int off=32;off>0;off>>=1) v += __shfl_down(v,off,64);
        if(lane==0) red[wid*4+o]=v;
    }
    __syncthreads();
    if(threadIdx.x==0){
        float s[4], mx=-1e30f;
        for(int o=0;o<4;o++){
            int tt = t + offs[o];
            s[o] = (tt>=0 && tt<TX) ? (red[o]+red[4+o]+red[8+o]+red[12+o])*RSQ : -1e9f;
            mx = fmaxf(mx, s[o]);
        }
        float sum=0;
        for(int o=0;o<4;o++){ s[o]=expf(s[o]-mx); sum+=s[o]; }
        for(int o=0;o<4;o++) wts[o]=s[o]/sum;
    }
    __syncthreads();
    float p3 = pi[tok*SX+3];
    __shared__ float row[DIMX];
    __shared__ float sbuf[4];
    float lsum = 0;
    for(int d=threadIdx.x; d<DIMX; d+=blockDim.x){
        float m = 0;
        #pragma unroll
        for(int o=0;o<4;o++){
            int tt = t + offs[o];
            if(tt>=0 && tt<TX) m += wts[o]*vv[((long)(b*TX+tt))*DIMX + d];
        }
        m *= p3;
        row[d] = m; lsum += m;
    }
    float mean = block_reduce_sum(lsum, sbuf) * (1.0f/DIMX);
    float lv = 0;
    for(int d=threadIdx.x; d<DIMX; d+=blockDim.x){ float dv=row[d]-mean; lv+=dv*dv; }
    float var = block_reduce_sum(lv, sbuf) * (1.0f/DIMX);
    float rstd = rsqrtf(var + 1e-5f);
    for(int d=threadIdx.x; d<DIMX; d+=blockDim.x)
        msg[(long)tok*DIMX+d] = (row[d]-mean)*rstd*g3[d] + b3[d];
}

// ---------------- fused write-update + ln(5) + add 0.1*so ----------------
__global__ void k_update(const float* __restrict__ dlamz, const float* __restrict__ mhat,
                         const float* __restrict__ muwn, const float* __restrict__ so,
                         const float* __restrict__ pi, float* __restrict__ mu,
                         float* __restrict__ lam,
                         const float* __restrict__ g5, const float* __restrict__ b5){
    int tok = blockIdx.x;
    float g = pi[tok*SX+4];
    __shared__ float row[DIMX];
    __shared__ float sbuf[4];
    float lsum = 0;
    for(int d=threadIdx.x; d<DIMX; d+=blockDim.x){
        long i = (long)tok*DIMX + d;
        float dl = g * softplus_f(dlamz[i]);
        float l  = lam[i];
        float ln_ = l + dl;
        float v = (l*muwn[i] + dl*mhat[i]) / ln_;
        lam[i] = ln_;
        row[d] = v; lsum += v;
    }
    float mean = block_reduce_sum(lsum, sbuf) * (1.0f/DIMX);
    float lv = 0;
    for(int d=threadIdx.x; d<DIMX; d+=blockDim.x){ float dv=row[d]-mean; lv+=dv*dv; }
    float var = block_reduce_sum(lv, sbuf) * (1.0f/DIMX);
    float rstd = rsqrtf(var + 1e-5f);
    for(int d=threadIdx.x; d<DIMX; d+=blockDim.x){
        long i = (long)tok*DIMX + d;
        mu[i] = (row[d]-mean)*rstd*g5[d] + b5[d] + 0.1f*so[i];
    }
}

extern "C" void kernel_launch(void* const* d_in, const int* in_sizes, int n_in,
                              void* d_out, int out_size, void* d_ws, size_t ws_size,
                              hipStream_t stream){
    const int*   x       = (const int*)  d_in[0];
    const float* emb_w   = (const float*)d_in[1];
    const float* pos_w   = (const float*)d_in[2];
    const float* mu_w    = (const float*)d_in[3];
    const float* mu_b    = (const float*)d_in[4];
    const float* lam_w   = (const float*)d_in[5];
    const float* lam_b   = (const float*)d_in[6];
    const float* tr_w1   = (const float*)d_in[7];
    const float* tr_b1   = (const float*)d_in[8];
    const float* tr_w2   = (const float*)d_in[9];
    const float* tr_b2   = (const float*)d_in[10];
    const float* bank_w1 = (const float*)d_in[11];
    const float* bank_b1 = (const float*)d_in[12];
    const float* bank_w2 = (const float*)d_in[13];
    const float* bank_b2 = (const float*)d_in[14];
    const float* ev_w    = (const float*)d_in[15];
    const float* ev_b    = (const float*)d_in[16];
    const float* rt_q    = (const float*)d_in[17];
    const float* rt_k    = (const float*)d_in[18];
    const float* rt_v    = (const float*)d_in[19];
    const float* wr_lam_w= (const float*)d_in[20];
    const float* wr_lam_b= (const float*)d_in[21];
    const float* wr_mu_w = (const float*)d_in[22];
    const float* wr_mu_b = (const float*)d_in[23];
    const float* ln_g    = (const float*)d_in[24];
    const float* ln_b    = (const float*)d_in[25];

    float* ws  = (float*)d_ws;
    float* h   = ws;                            // BT*DIMX
    float* mu  = h   + (long)BT*DIMX;           // BT*DIMX
    float* lam = mu  + (long)BT*DIMX;           // BT*DIMX
    float* mun = lam + (long)BT*DIMX;           // BT*DIMX
    float* so  = mun + (long)BT*DIMX;           // (BT+1)*DIMX  (+1 dummy row for padded scatter)
    float* t1  = so  + (long)(BT+1)*DIMX;       // BT*2*DIMX
    float* hb  = t1  + (long)BT*2*DIMX;         // BT*FFX
    float* pi  = hb  + (long)BT*FFX;            // BT*SX
    float* piv = pi  + (long)BT*SX;             // BT*SX
    int*   cnt = (int*)(piv + (long)BT*SX);     // 8 ints
    int*   gidx= cnt + 8;                       // SX*BT ints
    __bf16* emb16 = (__bf16*)(gidx + SX*BT);    // VX*DIMX bf16 (16B-aligned by construction)
    // aliases (lifetimes disjoint)
    float* q     = t1;
    float* kk    = t1 + (long)BT*DIMX;
    float* vv    = h;
    float* msg   = hb;
    float* dlamz = hb + (long)BT*DIMX;
    float* mhat  = hb + 2L*BT*DIMX;

    dim3 blk(256);
    dim3 g768(DIMX/64, BT/64);

    k_embed<<<BT, blk, 0, stream>>>(x, emb_w, pos_w, h, pi);
    k_init_lists<<<(SX*BT+255)/256, blk, 0, stream>>>(gidx, cnt);
    k_cvt_bf16<<<(VX*DIMX/4+255)/256, blk, 0, stream>>>(emb_w, emb16, (long)VX*DIMX);
    k_gemm_nn<0><<<g768, blk, 0, stream>>>(h, mu_w,  mu_b,  mu,  BT, DIMX, DIMX);
    k_gemm_nn<2><<<g768, blk, 0, stream>>>(h, lam_w, lam_b, lam, BT, DIMX, DIMX);

    for(int step=0; step<3; step++){
        // transition MLP -> pi_ev
        k_gemm_nn<1><<<dim3(2*DIMX/64, BT/64), blk, 0, stream>>>(mu, tr_w1, tr_b1, t1, BT, 2*DIMX, DIMX);
        k_trans<<<BT, blk, 0, stream>>>(t1, tr_w2, tr_b2, pi, piv);
        // bank MoE — gathered by live expert lists (pi sparsity: step0 1/6, later 2/6)
        k_ln<<<BT, blk, 0, stream>>>(mu, mun, ln_g+0*DIMX, ln_b+0*DIMX);
        hipMemsetAsync(so, 0, (size_t)(BT+1)*DIMX*sizeof(float), stream);
        for(int s=0; s<SX; s++){
            k_gemm_g1<<<dim3(FFX/64, BT/64), blk, 0, stream>>>(
                mun, bank_w1+(long)s*DIMX*FFX, bank_b1+(long)s*FFX, hb, gidx, cnt, s, FFX, DIMX);
            k_gemm_g2<<<dim3(DIMX/64, BT/64), blk, 0, stream>>>(
                hb, bank_w2+(long)s*FFX*DIMX, bank_b2+(long)s*DIMX, so, pi, gidx, cnt, s, DIMX, FFX);
        }
        k_ln<<<BT, blk, 0, stream>>>(so, so, ln_g+1*DIMX, ln_b+1*DIMX);
        // pi update + next step's expert lists
        k_fill_lists<<<(SX*BT+255)/256, blk, 0, stream>>>(gidx, cnt);
        k_pi_update<<<BT, blk, 0, stream>>>(mun, ev_w, ev_b, piv, pi, gidx, cnt);
        // routed attention
        k_ln<<<BT, blk, 0, stream>>>(mu, mun, ln_g+2*DIMX, ln_b+2*DIMX);
        k_gemm_nn<0><<<g768, blk, 0, stream>>>(mun, rt_q, nullptr, q,  BT, DIMX, DIMX);
        k_gemm_nn<0><<<g768, blk, 0, stream>>>(mun, rt_k, nullptr, kk, BT, DIMX, DIMX);
        k_gemm_nn<0><<<g768, blk, 0, stream>>>(mun, rt_v, nullptr, vv, BT, DIMX, DIMX);
        k_attn<<<BT, blk, 0, stream>>>(q, kk, vv, pi, ln_g+3*DIMX, ln_b+3*DIMX, msg);
        // write update
        k_ln<<<BT, blk, 0, stream>>>(mu, mun, ln_g+4*DIMX, ln_b+4*DIMX);
        k_gemm_nn<0><<<g768, blk, 0, stream>>>(msg, wr_lam_w, wr_lam_b, dlamz, BT, DIMX, DIMX);
        k_gemm_nn<0><<<g768, blk, 0, stream>>>(msg, wr_mu_w,  wr_mu_b,  mhat,  BT, DIMX, DIMX);
        k_update<<<BT, blk, 0, stream>>>(dlamz, mhat, mun, so, pi, mu, lam, ln_g+5*DIMX, ln_b+5*DIMX);
    }
    // final LN + logits (bf16 MFMA)
    k_ln<<<BT, blk, 0, stream>>>(mu, mun, ln_g+6*DIMX, ln_b+6*DIMX);
    k_logits_mfma<<<dim3(VX/128, BT/128), blk, 0, stream>>>(mun, emb16, (float*)d_out,
                                                            0.03608439182435161f);
}